// Round 1
// baseline (320.215 us; speedup 1.0000x reference)
//
#include <hip/hip_runtime.h>
#include <stdint.h>

#define T_DIM 64
#define A_DIM 64
#define F_DIM 512
#define H_DIM 1024
#define N_DIM 512
#define E_DIM 4
#define NTOK 4096       // T*A
#define NTOK_PAD 4224   // +128 rows slack so tiles can over-read

typedef __attribute__((ext_vector_type(8))) short short8;
typedef __attribute__((ext_vector_type(4))) short short4v;
typedef __attribute__((ext_vector_type(4))) float f32x4;

// ---------- bf16 helpers (RNE) ----------
__device__ __forceinline__ unsigned short f2bf(float x) {
  unsigned u = __float_as_uint(x);
  u += 0x7fffu + ((u >> 16) & 1u);
  return (unsigned short)(u >> 16);
}
__device__ __forceinline__ float bf2f(unsigned short h) {
  return __uint_as_float(((unsigned)h) << 16);
}
__device__ __forceinline__ void split_bf(float x, short& hi, short& lo) {
  unsigned short h = f2bf(x);
  hi = (short)h;
  lo = (short)f2bf(x - bf2f(h));
}

// ---------- async global->LDS, 16B per lane ----------
__device__ __forceinline__ void gload_lds16(const void* g, void* l) {
  __builtin_amdgcn_global_load_lds(
      (const __attribute__((address_space(1))) unsigned int*)g,
      (__attribute__((address_space(3))) unsigned int*)l, 16, 0, 0);
}

// ---------- routing ----------
__global__ void k_route_init(int* cnt, int* cur) {
  int i = threadIdx.x;
  if (i < E_DIM) { cnt[i] = 0; cur[i] = 0; }
}

__global__ void k_route_count(const int* __restrict__ at, int* __restrict__ cnt) {
  int i = blockIdx.x * 256 + threadIdx.x;
  if (i < NTOK) atomicAdd(&cnt[at[i]], 1);
}

__global__ void k_route_off(const int* __restrict__ cnt, int* __restrict__ off) {
  if (threadIdx.x == 0) {
    int a = 0;
    for (int e = 0; e < E_DIM; ++e) { off[e] = a; a += cnt[e]; }
    off[E_DIM] = a;
  }
}

// one block per token: claim a sorted slot, record idx, gather+split obs row
__global__ void k_gather(const float* __restrict__ obs, const int* __restrict__ at,
                         const int* __restrict__ off, int* __restrict__ cur,
                         int* __restrict__ idx,
                         short* __restrict__ oH, short* __restrict__ oL) {
  __shared__ int s_pos;
  int t = blockIdx.x;
  int e = at[t];
  if (threadIdx.x == 0) s_pos = off[e] + atomicAdd(&cur[e], 1);
  __syncthreads();
  int pos = s_pos;
  if (threadIdx.x == 0) idx[pos] = t;
  const float* src = obs + (size_t)t * F_DIM;
  int base = threadIdx.x * 8;   // 64 threads * 8 = 512
  float4 v0 = *(const float4*)(src + base);
  float4 v1 = *(const float4*)(src + base + 4);
  float xs[8] = {v0.x, v0.y, v0.z, v0.w, v1.x, v1.y, v1.z, v1.w};
  short8 hh, ll;
#pragma unroll
  for (int i = 0; i < 8; ++i) {
    short h, l;
    split_bf(xs[i], h, l);
    hh[i] = h; ll[i] = l;
  }
  *(short8*)&oH[(size_t)pos * F_DIM + base] = hh;
  *(short8*)&oL[(size_t)pos * F_DIM + base] = ll;
}

// ---------- weight transpose + hi/lo split:  W[e][k][n] -> WT[e][n][k] ----------
__global__ void k_wsplit(const float* __restrict__ W, short* __restrict__ Th,
                         short* __restrict__ Tl, int K, int N) {
  int e  = blockIdx.z;
  int n0 = blockIdx.x * 64;
  int k0 = blockIdx.y * 64;
  __shared__ float tile[64][65];
  const float* w = W + (size_t)e * K * N;
  int tr = threadIdx.x >> 4;   // 0..15
  int tc = threadIdx.x & 15;   // 0..15
#pragma unroll
  for (int i = 0; i < 4; ++i) {
    int kk = k0 + i * 16 + tr;
    float4 v = *(const float4*)(w + (size_t)kk * N + n0 + tc * 4);
    tile[i * 16 + tr][tc * 4 + 0] = v.x;
    tile[i * 16 + tr][tc * 4 + 1] = v.y;
    tile[i * 16 + tr][tc * 4 + 2] = v.z;
    tile[i * 16 + tr][tc * 4 + 3] = v.w;
  }
  __syncthreads();
#pragma unroll
  for (int i = 0; i < 4; ++i) {
    int nr = i * 16 + tr;
    size_t ob = ((size_t)e * N + (n0 + nr)) * K + k0 + tc * 4;
    short4v hh, ll;
#pragma unroll
    for (int j = 0; j < 4; ++j) {
      float x = tile[tc * 4 + j][nr];
      short h, l;
      split_bf(x, h, l);
      hh[j] = h; ll[j] = l;
    }
    *(short4v*)&Th[ob] = hh;
    *(short4v*)&Tl[ob] = ll;
  }
}

// ---------- grouped GEMM: C[rows of expert e] = act(A * W_e^T + b_e) ----------
// A planes: [row][k] (hi,lo).  B planes: [e][n][k] (hi,lo).
// split product: ah*bh + ah*bl + al*bh  (~2^-16 relative error)
template <int K, int NOUT, bool RELU, bool FINAL>
__launch_bounds__(256, 2)
__global__ void k_gemm(const short* __restrict__ Ah, const short* __restrict__ Al,
                       const short* __restrict__ Bh, const short* __restrict__ Bl,
                       const float* __restrict__ bias,
                       short* __restrict__ Ch, short* __restrict__ Cl,
                       float* __restrict__ outF, const int* __restrict__ idx,
                       const int* __restrict__ offs, const int* __restrict__ cnts) {
  constexpr int MT = NTOK / 128;   // over-provisioned m-tiles per expert
  constexpr int NT = NOUT / 128;
  int bx  = blockIdx.x;
  int e   = bx / (MT * NT);
  int rem = bx % (MT * NT);
  int mt  = rem / NT;
  int nt  = rem % NT;
  int cnt = cnts[e];
  if (mt * 128 >= cnt) return;          // uniform per block
  int off     = offs[e];
  int row0    = off + mt * 128;
  int row_end = off + cnt;
  int ncol0   = nt * 128;

  // [buf][plane: Ah,Al,Bh,Bl][128 rows x 32 k]  = 64 KiB
  __shared__ short lds[2][4][128 * 32];

  int tid  = threadIdx.x;
  int wave = tid >> 6, ln = tid & 63;
  int wr = wave >> 1, wc = wave & 1;

  const short* __restrict__ aP0 = Ah;
  const short* __restrict__ aP1 = Al;
  const short* __restrict__ bP0 = Bh + (size_t)e * NOUT * K;
  const short* __restrict__ bP1 = Bl + (size_t)e * NOUT * K;

  int srow = ln >> 2;        // row within 16-row chunk
  int ksh  = (ln & 3) * 8;   // shorts offset within 64B row (16B per lane)

  auto stage = [&](int buf, int ks) {
    int k0 = ks * 32;
    const short* base;
    int rb;
    if (wave == 0)      { base = aP0; rb = row0;  }
    else if (wave == 1) { base = aP1; rb = row0;  }
    else if (wave == 2) { base = bP0; rb = ncol0; }
    else                { base = bP1; rb = ncol0; }
#pragma unroll
    for (int i = 0; i < 8; ++i) {
      int rowt = i * 16 + srow;
      const short* src = base + ((size_t)(rb + rowt) * K + k0 + ksh);
      gload_lds16(src, (void*)&lds[buf][wave][i * 512]);
    }
  };

  f32x4 acc[4][4] = {};
  int tm = ln & 15, kg = ln >> 4;

  stage(0, 0);
  __syncthreads();
  constexpr int NK = K / 32;
  for (int ks = 0; ks < NK; ++ks) {
    int curb = ks & 1;
    if (ks + 1 < NK) stage(curb ^ 1, ks + 1);   // async prefetch, flies during MFMA
    short8 ah[4], al[4], bh[4], bl[4];
#pragma unroll
    for (int i = 0; i < 4; ++i) {
      int ar = (wr * 64 + i * 16 + tm) * 32 + kg * 8;
      ah[i] = *(const short8*)&lds[curb][0][ar];
      al[i] = *(const short8*)&lds[curb][1][ar];
      int br = (wc * 64 + i * 16 + tm) * 32 + kg * 8;
      bh[i] = *(const short8*)&lds[curb][2][br];
      bl[i] = *(const short8*)&lds[curb][3][br];
    }
#pragma unroll
    for (int i = 0; i < 4; ++i)
#pragma unroll
      for (int j = 0; j < 4; ++j) {
        acc[i][j] = __builtin_amdgcn_mfma_f32_16x16x32_bf16(ah[i], bh[j], acc[i][j], 0, 0, 0);
        acc[i][j] = __builtin_amdgcn_mfma_f32_16x16x32_bf16(ah[i], bl[j], acc[i][j], 0, 0, 0);
        acc[i][j] = __builtin_amdgcn_mfma_f32_16x16x32_bf16(al[i], bh[j], acc[i][j], 0, 0, 0);
      }
    __syncthreads();   // drains vmcnt (prefetch done) + protects buffer reuse
  }

  // epilogue: C/D layout col=lane&15, row=(lane>>4)*4+q  [m89-verified]
  int lcol = ln & 15;
  int lrow = (ln >> 4) * 4;
#pragma unroll
  for (int j = 0; j < 4; ++j) {
    int col = ncol0 + wc * 64 + j * 16 + lcol;
    float bv = bias[(size_t)e * NOUT + col];
#pragma unroll
    for (int i = 0; i < 4; ++i) {
      int grow_base = row0 + wr * 64 + i * 16 + lrow;
#pragma unroll
      for (int q = 0; q < 4; ++q) {
        int grow = grow_base + q;
        if (grow < row_end) {   // compact segments: predicate, no cross-expert races
          float x = acc[i][j][q] + bv;
          if (RELU) x = fmaxf(x, 0.0f);
          if (FINAL) {
            int token = idx[grow];
            outF[(size_t)token * NOUT + col] = x;
          } else {
            short h, l;
            split_bf(x, h, l);
            Ch[(size_t)grow * NOUT + col] = h;
            Cl[(size_t)grow * NOUT + col] = l;
          }
        }
      }
    }
  }
}

extern "C" void kernel_launch(void* const* d_in, const int* in_sizes, int n_in,
                              void* d_out, int out_size, void* d_ws, size_t ws_size,
                              hipStream_t stream) {
  (void)in_sizes; (void)n_in; (void)out_size; (void)ws_size;
  const float* obs = (const float*)d_in[0];
  const float* W1  = (const float*)d_in[1];
  const float* b1  = (const float*)d_in[2];
  const float* W2  = (const float*)d_in[3];
  const float* b2  = (const float*)d_in[4];
  const float* W3  = (const float*)d_in[5];
  const float* b3  = (const float*)d_in[6];
  const int*   at  = (const int*)d_in[7];
  float* out = (float*)d_out;

  // ---- carve workspace (≈77 MB) ----
  char* w = (char*)d_ws;
  auto carve = [&](size_t bytes) {
    char* p = w;
    w += (bytes + 255) & ~(size_t)255;
    return p;
  };
  int* cnt = (int*)carve(E_DIM * 4);
  int* cur = (int*)carve(E_DIM * 4);
  int* off = (int*)carve((E_DIM + 1) * 4);
  int* idx = (int*)carve(NTOK_PAD * 4);
  short* obsH = (short*)carve((size_t)NTOK_PAD * F_DIM * 2);
  short* obsL = (short*)carve((size_t)NTOK_PAD * F_DIM * 2);
  short* h1H  = (short*)carve((size_t)NTOK_PAD * H_DIM * 2);
  short* h1L  = (short*)carve((size_t)NTOK_PAD * H_DIM * 2);
  short* h2H  = (short*)carve((size_t)NTOK_PAD * H_DIM * 2);
  short* h2L  = (short*)carve((size_t)NTOK_PAD * H_DIM * 2);
  short* w1h  = (short*)carve((size_t)E_DIM * H_DIM * F_DIM * 2);
  short* w1l  = (short*)carve((size_t)E_DIM * H_DIM * F_DIM * 2);
  short* w2h  = (short*)carve((size_t)E_DIM * H_DIM * H_DIM * 2);
  short* w2l  = (short*)carve((size_t)E_DIM * H_DIM * H_DIM * 2);
  short* w3h  = (short*)carve((size_t)E_DIM * N_DIM * H_DIM * 2);
  short* w3l  = (short*)carve((size_t)E_DIM * N_DIM * H_DIM * 2);

  // ---- routing + input conversion ----
  k_route_init<<<1, 64, 0, stream>>>(cnt, cur);
  k_route_count<<<NTOK / 256, 256, 0, stream>>>(at, cnt);
  k_route_off<<<1, 64, 0, stream>>>(cnt, off);
  k_gather<<<NTOK, 64, 0, stream>>>(obs, at, off, cur, idx, obsH, obsL);

  // ---- weight transpose + split ----
  k_wsplit<<<dim3(H_DIM / 64, F_DIM / 64, E_DIM), 256, 0, stream>>>(W1, w1h, w1l, F_DIM, H_DIM);
  k_wsplit<<<dim3(H_DIM / 64, H_DIM / 64, E_DIM), 256, 0, stream>>>(W2, w2h, w2l, H_DIM, H_DIM);
  k_wsplit<<<dim3(N_DIM / 64, H_DIM / 64, E_DIM), 256, 0, stream>>>(W3, w3h, w3l, H_DIM, N_DIM);

  // ---- grouped GEMM layers ----
  k_gemm<F_DIM, H_DIM, true, false>
      <<<E_DIM * (NTOK / 128) * (H_DIM / 128), 256, 0, stream>>>(
          obsH, obsL, w1h, w1l, b1, h1H, h1L, nullptr, nullptr, off, cnt);
  k_gemm<H_DIM, H_DIM, true, false>
      <<<E_DIM * (NTOK / 128) * (H_DIM / 128), 256, 0, stream>>>(
          h1H, h1L, w2h, w2l, b2, h2H, h2L, nullptr, nullptr, off, cnt);
  k_gemm<H_DIM, N_DIM, false, true>
      <<<E_DIM * (NTOK / 128) * (N_DIM / 128), 256, 0, stream>>>(
          h2H, h2L, w3h, w3l, b3, nullptr, nullptr, out, idx, off, cnt);
}

// Round 4
// 215.585 us; speedup vs baseline: 1.4853x; 1.4853x over previous
//
#include <hip/hip_runtime.h>
#include <stdint.h>

#define T_DIM 64
#define A_DIM 64
#define F_DIM 512
#define H_DIM 1024
#define N_DIM 512
#define E_DIM 4
#define NTOK 4096
#define NTOK_PAD 4224   // +128 rows slack so 64-row tiles can over-read
#define NSLOT 72        // >= max sum_e ceil(cnt_e/64) = 67, and NSLOT*NT % 8 == 0

typedef __attribute__((ext_vector_type(8))) short short8;
typedef __attribute__((ext_vector_type(4))) short short4v;
typedef __attribute__((ext_vector_type(4))) float f32x4;

// ---------- bf16 helpers (RNE) ----------
__device__ __forceinline__ unsigned short f2bf(float x) {
  unsigned u = __float_as_uint(x);
  u += 0x7fffu + ((u >> 16) & 1u);
  return (unsigned short)(u >> 16);
}
__device__ __forceinline__ float bf2f(unsigned short h) {
  return __uint_as_float(((unsigned)h) << 16);
}
__device__ __forceinline__ void split_bf(float x, short& hi, short& lo) {
  unsigned short h = f2bf(x);
  hi = (short)h;
  lo = (short)f2bf(x - bf2f(h));
}

// ---------- async global->LDS, 16B per lane ----------
__device__ __forceinline__ void gload_lds16(const void* g, void* l) {
  __builtin_amdgcn_global_load_lds(
      (const __attribute__((address_space(1))) unsigned int*)g,
      (__attribute__((address_space(3))) unsigned int*)l, 16, 0, 0);
}

// ---------- routing: histogram + prefix + per-token position + slot worklist ----------
// single block, 1024 threads (16 waves), no global atomics
__global__ __launch_bounds__(1024) void k_route(const int* __restrict__ at,
                                                int* __restrict__ pos,
                                                int4* __restrict__ slots) {
  __shared__ int wt[16][4];    // per-wave totals
  __shared__ int woff[16][4];  // exclusive wave offsets
  __shared__ int soff[4];      // expert segment starts
  int tid = threadIdx.x;
  int w = tid >> 6, ln = tid & 63;

  int4 a = ((const int4*)at)[tid];   // tokens 4*tid .. 4*tid+3
  int c[4] = {0, 0, 0, 0};
  c[a.x]++; c[a.y]++; c[a.z]++; c[a.w]++;

  int inc[4];
#pragma unroll
  for (int e = 0; e < 4; ++e) inc[e] = c[e];
#pragma unroll
  for (int d = 1; d < 64; d <<= 1) {
#pragma unroll
    for (int e = 0; e < 4; ++e) {
      int u = __shfl_up(inc[e], d, 64);
      if (ln >= d) inc[e] += u;
    }
  }
  if (ln == 63) {
#pragma unroll
    for (int e = 0; e < 4; ++e) wt[w][e] = inc[e];
  }
  __syncthreads();
  if (tid == 0) {
    int tot[4] = {0, 0, 0, 0};
    for (int i = 0; i < 16; ++i)
      for (int e = 0; e < 4; ++e) { woff[i][e] = tot[e]; tot[e] += wt[i][e]; }
    int acc = 0;
    int sbase[4];
    for (int e = 0; e < 4; ++e) { sbase[e] = acc; soff[e] = acc; acc += tot[e]; }
    // build slot worklist
    int si = 0;
    for (int e = 0; e < 4; ++e) {
      int cnt = tot[e];
      for (int m = 0; m * 64 < cnt; ++m) {
        int4 s;
        s.x = sbase[e] + m * 64;
        s.y = (cnt - m * 64) < 64 ? (cnt - m * 64) : 64;
        s.z = e; s.w = 0;
        slots[si++] = s;
      }
    }
    int4 z; z.x = 0; z.y = 0; z.z = 0; z.w = 0;
    while (si < NSLOT) slots[si++] = z;
  }
  __syncthreads();
  int excl[4];
#pragma unroll
  for (int e = 0; e < 4; ++e) excl[e] = soff[e] + woff[w][e] + inc[e] - c[e];
  int es[4] = {a.x, a.y, a.z, a.w};
#pragma unroll
  for (int k = 0; k < 4; ++k) {
    int e = es[k];
    pos[tid * 4 + k] = excl[e];
    excl[e]++;
  }
}

// ---------- gather: scatter obs rows to expert-sorted hi/lo planes ----------
__global__ void k_gather(const float* __restrict__ obs, const int* __restrict__ pos,
                         int* __restrict__ idx,
                         short* __restrict__ oH, short* __restrict__ oL) {
  int tid = threadIdx.x;               // 256
  int t = blockIdx.x * 4 + (tid >> 6); // token
  int ln = tid & 63;
  int p = pos[t];
  if (ln == 0) idx[p] = t;
  const float* src = obs + (size_t)t * F_DIM;
  int base = ln * 8;                   // 64 lanes * 8 = 512
  float4 v0 = *(const float4*)(src + base);
  float4 v1 = *(const float4*)(src + base + 4);
  float xs[8] = {v0.x, v0.y, v0.z, v0.w, v1.x, v1.y, v1.z, v1.w};
  short8 hh, ll;
#pragma unroll
  for (int i = 0; i < 8; ++i) {
    short h, l;
    split_bf(xs[i], h, l);
    hh[i] = h; ll[i] = l;
  }
  *(short8*)&oH[(size_t)p * F_DIM + base] = hh;
  *(short8*)&oL[(size_t)p * F_DIM + base] = ll;
}

// ---------- weight transpose + hi/lo split:  W[e][k][n] -> WT[e][n][k] ----------
__global__ void k_wsplit(const float* __restrict__ W, short* __restrict__ Th,
                         short* __restrict__ Tl, int K, int N) {
  int e  = blockIdx.z;
  int n0 = blockIdx.x * 64;
  int k0 = blockIdx.y * 64;
  __shared__ float tile[64][65];
  const float* w = W + (size_t)e * K * N;
  int tr = threadIdx.x >> 4;
  int tc = threadIdx.x & 15;
#pragma unroll
  for (int i = 0; i < 4; ++i) {
    int kk = k0 + i * 16 + tr;
    float4 v = *(const float4*)(w + (size_t)kk * N + n0 + tc * 4);
    tile[i * 16 + tr][tc * 4 + 0] = v.x;
    tile[i * 16 + tr][tc * 4 + 1] = v.y;
    tile[i * 16 + tr][tc * 4 + 2] = v.z;
    tile[i * 16 + tr][tc * 4 + 3] = v.w;
  }
  __syncthreads();
#pragma unroll
  for (int i = 0; i < 4; ++i) {
    int nr = i * 16 + tr;
    size_t ob = ((size_t)e * N + (n0 + nr)) * K + k0 + tc * 4;
    short4v hh, ll;
#pragma unroll
    for (int j = 0; j < 4; ++j) {
      float x = tile[tc * 4 + j][nr];
      short h, l;
      split_bf(x, h, l);
      hh[j] = h; ll[j] = l;
    }
    *(short4v*)&Th[ob] = hh;
    *(short4v*)&Tl[ob] = ll;
  }
}

// ---------- grouped GEMM: 64x128 tile, 4 waves (2x2), double-buffered LDS ----------
// A planes [row][k] (hi,lo); B planes [e][n][k] (hi,lo)
// split product: ah*bh + ah*bl + al*bh  (~2^-16 relative)
template <int K, int NOUT, bool RELU, bool FINAL>
__launch_bounds__(256, 3)
__global__ void k_gemm(const short* __restrict__ Ah, const short* __restrict__ Al,
                       const short* __restrict__ Bh, const short* __restrict__ Bl,
                       const float* __restrict__ bias,
                       short* __restrict__ Ch, short* __restrict__ Cl,
                       float* __restrict__ outF, const int* __restrict__ idx,
                       const int4* __restrict__ slots) {
  constexpr int NT  = NOUT / 128;
  constexpr int NWG = NSLOT * NT;
  // XCD-chunked bijective swizzle: hw-consecutive blocks round-robin XCDs;
  // give each XCD a contiguous logical range -> n-tiles of one slot share L2
  int wg   = (blockIdx.x & 7) * (NWG / 8) + (blockIdx.x >> 3);
  int slot = wg / NT;
  int nt   = wg % NT;
  int4 s = slots[slot];
  int rows = s.y;
  if (rows == 0) return;
  int row0 = s.x, e = s.z, row_end = row0 + rows;
  int ncol0 = nt * 128;

  // per buffer (shorts): [Ah 64x32 @0][Al @2048][Bh 128x32 @4096][Bl @8192] = 24 KiB
  __shared__ short lds[2][12288];

  int tid = threadIdx.x, wave = tid >> 6, ln = tid & 63;
  const short* bPh = Bh + (size_t)e * NOUT * K;
  const short* bPl = Bl + (size_t)e * NOUT * K;

  // precompute the 6 loop-invariant staging source pointers (16B chunk per lane)
  const short* srcb[6];
#pragma unroll
  for (int r = 0; r < 6; ++r) {
    int g = r * 256 + tid;   // chunk id 0..1535; plane uniform per (r,wave)
    if (g < 256)       { int wc = g;        srcb[r] = Ah  + (size_t)(row0  + (wc >> 2)) * K + (wc & 3) * 8; }
    else if (g < 512)  { int wc = g - 256;  srcb[r] = Al  + (size_t)(row0  + (wc >> 2)) * K + (wc & 3) * 8; }
    else if (g < 1024) { int wc = g - 512;  srcb[r] = bPh + (size_t)(ncol0 + (wc >> 2)) * K + (wc & 3) * 8; }
    else               { int wc = g - 1024; srcb[r] = bPl + (size_t)(ncol0 + (wc >> 2)) * K + (wc & 3) * 8; }
  }

  // LDS dest is wave-uniform base (+ lane*16 applied by HW) [m104/m108]
  int wbase = (tid & ~63) * 8;   // shorts; chunk base of this wave's 64 lanes

  auto stage = [&](int buf, int ks) {
    int k0 = ks * 32;
#pragma unroll
    for (int r = 0; r < 6; ++r)
      gload_lds16(srcb[r] + k0, (void*)&lds[buf][r * 2048 + wbase]);
  };

  f32x4 acc[2][4] = {};
  int wr = wave >> 1, wcn = wave & 1;
  int tm = ln & 15, kg = ln >> 4;

  stage(0, 0);
  __syncthreads();
  constexpr int NK = K / 32;
  for (int ks = 0; ks < NK; ++ks) {
    int cb = ks & 1;
    if (ks + 1 < NK) stage(cb ^ 1, ks + 1);   // async prefetch during MFMA
    short8 ah[2], al[2], bh[4], bl[4];
#pragma unroll
    for (int i = 0; i < 2; ++i) {
      int ar = (wr * 32 + i * 16 + tm) * 32 + kg * 8;
      ah[i] = *(const short8*)&lds[cb][ar];
      al[i] = *(const short8*)&lds[cb][2048 + ar];
    }
#pragma unroll
    for (int j = 0; j < 4; ++j) {
      int br = (wcn * 64 + j * 16 + tm) * 32 + kg * 8;
      bh[j] = *(const short8*)&lds[cb][4096 + br];
      bl[j] = *(const short8*)&lds[cb][8192 + br];
    }
#pragma unroll
    for (int i = 0; i < 2; ++i)
#pragma unroll
      for (int j = 0; j < 4; ++j) {
        acc[i][j] = __builtin_amdgcn_mfma_f32_16x16x32_bf16(ah[i], bh[j], acc[i][j], 0, 0, 0);
        acc[i][j] = __builtin_amdgcn_mfma_f32_16x16x32_bf16(ah[i], bl[j], acc[i][j], 0, 0, 0);
        acc[i][j] = __builtin_amdgcn_mfma_f32_16x16x32_bf16(al[i], bh[j], acc[i][j], 0, 0, 0);
      }
    __syncthreads();   // drains vmcnt (prefetch landed) + protects buffer reuse
  }

  // epilogue: C/D layout col=lane&15, row=(lane>>4)*4+q  [m89-verified]
  int lcol = ln & 15;
  int lrow4 = (ln >> 4) * 4;
#pragma unroll
  for (int j = 0; j < 4; ++j) {
    int col = ncol0 + wcn * 64 + j * 16 + lcol;
    float bv = bias[(size_t)e * NOUT + col];
#pragma unroll
    for (int i = 0; i < 2; ++i) {
      int gr0 = row0 + wr * 32 + i * 16 + lrow4;
#pragma unroll
      for (int q = 0; q < 4; ++q) {
        int grow = gr0 + q;
        if (grow < row_end) {   // compact segments: predicate, no races
          float x = acc[i][j][q] + bv;
          if (RELU) x = fmaxf(x, 0.0f);
          if (FINAL) {
            int token = idx[grow];
            outF[(size_t)token * NOUT + col] = x;
          } else {
            short h, l;
            split_bf(x, h, l);
            Ch[(size_t)grow * NOUT + col] = h;
            Cl[(size_t)grow * NOUT + col] = l;
          }
        }
      }
    }
  }
}

extern "C" void kernel_launch(void* const* d_in, const int* in_sizes, int n_in,
                              void* d_out, int out_size, void* d_ws, size_t ws_size,
                              hipStream_t stream) {
  (void)in_sizes; (void)n_in; (void)out_size; (void)ws_size;
  const float* obs = (const float*)d_in[0];
  const float* W1  = (const float*)d_in[1];
  const float* b1  = (const float*)d_in[2];
  const float* W2  = (const float*)d_in[3];
  const float* b2  = (const float*)d_in[4];
  const float* W3  = (const float*)d_in[5];
  const float* b3  = (const float*)d_in[6];
  const int*   at  = (const int*)d_in[7];
  float* out = (float*)d_out;

  // ---- carve workspace ----
  char* w = (char*)d_ws;
  auto carve = [&](size_t bytes) {
    char* p = w;
    w += (bytes + 255) & ~(size_t)255;
    return p;
  };
  int*  pos   = (int*)carve(NTOK * 4);
  int4* slots = (int4*)carve(NSLOT * 16);
  int*  idx   = (int*)carve(NTOK_PAD * 4);
  short* obsH = (short*)carve((size_t)NTOK_PAD * F_DIM * 2);
  short* obsL = (short*)carve((size_t)NTOK_PAD * F_DIM * 2);
  short* h1H  = (short*)carve((size_t)NTOK_PAD * H_DIM * 2);
  short* h1L  = (short*)carve((size_t)NTOK_PAD * H_DIM * 2);
  short* h2H  = (short*)carve((size_t)NTOK_PAD * H_DIM * 2);
  short* h2L  = (short*)carve((size_t)NTOK_PAD * H_DIM * 2);
  short* w1h  = (short*)carve((size_t)E_DIM * H_DIM * F_DIM * 2);
  short* w1l  = (short*)carve((size_t)E_DIM * H_DIM * F_DIM * 2);
  short* w2h  = (short*)carve((size_t)E_DIM * H_DIM * H_DIM * 2);
  short* w2l  = (short*)carve((size_t)E_DIM * H_DIM * H_DIM * 2);
  short* w3h  = (short*)carve((size_t)E_DIM * N_DIM * H_DIM * 2);
  short* w3l  = (short*)carve((size_t)E_DIM * N_DIM * H_DIM * 2);

  // ---- routing (1 block) + gather (no atomics) ----
  k_route<<<1, 1024, 0, stream>>>(at, pos, slots);
  k_gather<<<NTOK / 4, 256, 0, stream>>>(obs, pos, idx, obsH, obsL);

  // ---- weight transpose + split ----
  k_wsplit<<<dim3(H_DIM / 64, F_DIM / 64, E_DIM), 256, 0, stream>>>(W1, w1h, w1l, F_DIM, H_DIM);
  k_wsplit<<<dim3(H_DIM / 64, H_DIM / 64, E_DIM), 256, 0, stream>>>(W2, w2h, w2l, H_DIM, H_DIM);
  k_wsplit<<<dim3(N_DIM / 64, H_DIM / 64, E_DIM), 256, 0, stream>>>(W3, w3h, w3l, H_DIM, N_DIM);

  // ---- grouped GEMM layers (64x128 tiles, exact worklist) ----
  k_gemm<F_DIM, H_DIM, true, false>
      <<<NSLOT * (H_DIM / 128), 256, 0, stream>>>(
          obsH, obsL, w1h, w1l, b1, h1H, h1L, nullptr, nullptr, slots);
  k_gemm<H_DIM, H_DIM, true, false>
      <<<NSLOT * (H_DIM / 128), 256, 0, stream>>>(
          h1H, h1L, w2h, w2l, b2, h2H, h2L, nullptr, nullptr, slots);
  k_gemm<H_DIM, N_DIM, false, true>
      <<<NSLOT * (N_DIM / 128), 256, 0, stream>>>(
          h2H, h2L, w3h, w3l, b3, nullptr, nullptr, out, idx, slots);
}